// Round 5
// baseline (11327.376 us; speedup 1.0000x reference)
//
#include <hip/hip_runtime.h>

// StructureModule on MI355X — round 8: persistent mega-kernel, v2.
//  - contention-free flag-array grid barrier (round-7's single-counter
//    fetch_add serialized 256 cross-XCD RMWs ~30us/barrier)
//  - 512-thread blocks; half-block workers: attention = 1 i/worker (512
//    concurrent, 8 waves/CU), Wo split-K9 (432 workers), FFN2 split-K8 (384)
//  - XOR-swizzled wgt LDS layout (fixes 1.69e7 bank conflicts on writes)

constexpr int N    = 512;
constexpr int CS   = 384;
constexpr int CZ   = 128;
constexpr int CH   = 16;
constexpr int H    = 12;
constexpr int L    = 8;
constexpr int RECY = 2;
constexpr int HCH  = H * CH;        // 192
constexpr int QKVN = 3 * HCH;       // 576
constexpr int OD   = H * (CH + CZ); // 1728
constexpr int FF   = 4 * CS;        // 1536
constexpr int MB   = 96;            // bias columns = L*H
constexpr int NB   = 256;           // persistent grid size (1 block/CU)
constexpr long long NN2 = (long long)N * N;

typedef __bf16 bf16x8 __attribute__((ext_vector_type(8)));
typedef float  f32x4  __attribute__((ext_vector_type(4)));
typedef unsigned short us8 __attribute__((ext_vector_type(8)));

__device__ __forceinline__ ushort f2bf(float f) {
    uint u = __builtin_bit_cast(uint, f);
    return (ushort)((u + 0x7fffu + ((u >> 16) & 1u)) >> 16);   // RNE
}
__device__ __forceinline__ float bf2f(ushort h) {
    uint u = ((uint)h) << 16;
    return __builtin_bit_cast(float, u);
}

// ------------------------------------------- flag-array grid barrier
// Each block owns flags[bid*16] (64B padded). Arrive: release-store the
// monotone target. Wait: threads 0..255 poll one flag each (parallel,
// read-only). No RMW contention.
__device__ __forceinline__ void gsync(uint* flags, uint target)
{
    __threadfence();                       // push this thread's writes
    __syncthreads();
    if (threadIdx.x == 0)
        __hip_atomic_store(flags + (size_t)blockIdx.x * 16, target,
                           __ATOMIC_RELEASE, __HIP_MEMORY_SCOPE_AGENT);
    if (threadIdx.x < NB) {
        while (__hip_atomic_load(flags + (size_t)threadIdx.x * 16,
                                 __ATOMIC_RELAXED, __HIP_MEMORY_SCOPE_AGENT) < target)
            __builtin_amdgcn_s_sleep(2);
    }
    __threadfence();                       // pull remote writes
    __syncthreads();
}

// ----------------------------------------------------- init s (f32 + bf16 copy)
__global__ __launch_bounds__(256) void init_s(
    const float* __restrict__ s_in, float* __restrict__ scur, ushort* __restrict__ sbf)
{
    int i = blockIdx.x * 256 + threadIdx.x;
    float v = s_in[i];
    scur[i] = v;
    sbf[i]  = f2bf(v);
}

// ------------------------------------------------------------- pack bq|bk|bv
__global__ __launch_bounds__(256) void pack_bqkv(
    const float* __restrict__ bq, const float* __restrict__ bk,
    const float* __restrict__ bv, float* __restrict__ bqkv)
{
    int idx = blockIdx.x * 256 + threadIdx.x;
    if (idx >= L * QKVN) return;
    int n = idx % QKVN, l = idx / QKVN;
    int sel = n / HCH, nn = n % HCH;
    const float* bp = sel == 0 ? bq : (sel == 1 ? bk : bv);
    bqkv[idx] = bp[l * HCH + nn];
}

// ---------------------- pack Wq|Wk|Wv transposed to bf16 [l][n][k] (n-major)
__global__ __launch_bounds__(256) void pack_qkv_t(
    const float* __restrict__ Wq, const float* __restrict__ Wk,
    const float* __restrict__ Wv, ushort* __restrict__ WqkvT)
{
    __shared__ float tile[32][33];
    const int l = blockIdx.z;
    const int k0 = blockIdx.x * 32, n0 = blockIdx.y * 32;
    const int tx = threadIdx.x & 31, ty = threadIdx.x >> 5;
    const int sel = n0 / HCH;
    const int nn0 = n0 - sel * HCH;
    const float* W = sel == 0 ? Wq : (sel == 1 ? Wk : Wv);
    #pragma unroll
    for (int r = 0; r < 32; r += 8)
        tile[ty + r][tx] = W[((size_t)l * CS + k0 + ty + r) * HCH + nn0 + tx];
    __syncthreads();
    #pragma unroll
    for (int r = 0; r < 32; r += 8)
        WqkvT[((size_t)l * QKVN + n0 + ty + r) * CS + k0 + tx] = f2bf(tile[tx][ty + r]);
}

// ------------- generic transpose+convert: (G,K,Nn) f32 -> (G,Nn,K) bf16
__global__ __launch_bounds__(256) void transpose_w(
    const float* __restrict__ in, ushort* __restrict__ out, int K, int Nn)
{
    __shared__ float tile[32][33];
    const int l = blockIdx.z;
    const float* ip = in + (size_t)l * K * Nn;
    ushort* op = out + (size_t)l * K * Nn;
    const int k0 = blockIdx.x * 32, n0 = blockIdx.y * 32;
    const int tx = threadIdx.x & 31, ty = threadIdx.x >> 5;
    #pragma unroll
    for (int r = 0; r < 32; r += 8)
        tile[ty + r][tx] = ip[(size_t)(k0 + ty + r) * Nn + n0 + tx];
    __syncthreads();
    #pragma unroll
    for (int r = 0; r < 32; r += 8)
        op[(size_t)(n0 + ty + r) * K + k0 + tx] = f2bf(tile[tx][ty + r]);
}

// -------------------------------------- WbT[m=l*12+h][c] = Wb[l][c][h] (bf16)
__global__ __launch_bounds__(256) void pack_wbt(
    const float* __restrict__ Wb, ushort* __restrict__ WbT)
{
    int idx = blockIdx.x * 256 + threadIdx.x;     // MB*CZ = 12288
    int m = idx >> 7, c = idx & 127;
    int l = m / H, h = m % H;
    WbT[idx] = f2bf(Wb[((size_t)l * CZ + c) * H + h]);
}

// -------------------- bias_all[m][ij] = sum_c WbT[m][c]*z[ij][c] + bb[m]
__global__ __launch_bounds__(256) void bias_gemm(
    const ushort* __restrict__ WbT, const float* __restrict__ z,
    const float* __restrict__ bb, ushort* __restrict__ bias_all)
{
    const int w = threadIdx.x >> 6, lane = threadIdx.x & 63;
    const int lm = lane & 15, kg = lane >> 4;
    const size_t ij0 = (size_t)blockIdx.x * 256 + (size_t)w * 64;
    __shared__ float bbs[MB];
    if (threadIdx.x < MB) bbs[threadIdx.x] = bb[threadIdx.x];
    __syncthreads();
    f32x4 acc[6][4];
    #pragma unroll
    for (int mt = 0; mt < 6; mt++)
        #pragma unroll
        for (int nt = 0; nt < 4; nt++) acc[mt][nt] = (f32x4){0.f, 0.f, 0.f, 0.f};
    #pragma unroll
    for (int kc = 0; kc < 4; kc++) {
        const int k = kc * 32 + kg * 8;
        bf16x8 b[4];
        #pragma unroll
        for (int nt = 0; nt < 4; nt++) {
            const float* zp = z + (ij0 + nt * 16 + lm) * CZ + k;
            float4 z0 = *(const float4*)zp, z1 = *(const float4*)(zp + 4);
            b[nt][0] = (__bf16)z0.x; b[nt][1] = (__bf16)z0.y;
            b[nt][2] = (__bf16)z0.z; b[nt][3] = (__bf16)z0.w;
            b[nt][4] = (__bf16)z1.x; b[nt][5] = (__bf16)z1.y;
            b[nt][6] = (__bf16)z1.z; b[nt][7] = (__bf16)z1.w;
        }
        #pragma unroll
        for (int mt = 0; mt < 6; mt++) {
            bf16x8 a = *(const bf16x8*)(WbT + (size_t)(mt * 16 + lm) * CZ + k);
            #pragma unroll
            for (int nt = 0; nt < 4; nt++)
                acc[mt][nt] = __builtin_amdgcn_mfma_f32_16x16x32_bf16(a, b[nt], acc[mt][nt], 0, 0, 0);
        }
    }
    #pragma unroll
    for (int mt = 0; mt < 6; mt++)
        #pragma unroll
        for (int nt = 0; nt < 4; nt++)
            #pragma unroll
            for (int r = 0; r < 4; r++) {
                int m = mt * 16 + kg * 4 + r;
                bias_all[(size_t)m * NN2 + ij0 + nt * 16 + lm] = f2bf(acc[mt][nt][r] + bbs[m]);
            }
}

// --------------------------------------------- device GEMM tile (dual K-chain)
// worker = 256 threads (tt), 4 waves, 64x64 output tile.
__device__ __forceinline__ void gemm_tile(
    const ushort* __restrict__ A, const ushort* __restrict__ Bt,
    const float* __restrict__ bias, float* __restrict__ C,
    ushort* __restrict__ Cbf, ushort* __restrict__ vTout,
    int M, int Nn, int K, int kper, int relu,
    int bx, int by, int bz, int tt)
{
    const int w = tt >> 6, lane = tt & 63;
    const int lm = lane & 15, kg = lane >> 4;
    const int m0 = by * 64 + w * 16;
    const int n0 = bx * 64;
    const int kbeg = bz * kper;
    const int kh = kper >> 1;                       // kper multiple of 64
    const ushort* Ap  = A  + (size_t)(m0 + lm) * K + kbeg + kg * 8;
    const ushort* Bp  = Bt + (size_t)(n0 + lm) * K + kbeg + kg * 8;
    f32x4 acc[4], ac2[4];
    #pragma unroll
    for (int ct = 0; ct < 4; ct++) {
        acc[ct] = (f32x4){0.f, 0.f, 0.f, 0.f};
        ac2[ct] = (f32x4){0.f, 0.f, 0.f, 0.f};
    }
    for (int k = 0; k < kh; k += 32) {
        bf16x8 a0 = *(const bf16x8*)(Ap + k);
        bf16x8 a1 = *(const bf16x8*)(Ap + kh + k);
        #pragma unroll
        for (int ct = 0; ct < 4; ct++) {
            bf16x8 b0 = *(const bf16x8*)(Bp + (size_t)ct * 16 * K + k);
            bf16x8 b1 = *(const bf16x8*)(Bp + (size_t)ct * 16 * K + kh + k);
            acc[ct] = __builtin_amdgcn_mfma_f32_16x16x32_bf16(a0, b0, acc[ct], 0, 0, 0);
            ac2[ct] = __builtin_amdgcn_mfma_f32_16x16x32_bf16(a1, b1, ac2[ct], 0, 0, 0);
        }
    }
    float* Cz = C ? C + (size_t)bz * M * Nn : nullptr;
    #pragma unroll
    for (int ct = 0; ct < 4; ct++) {
        int col = n0 + ct * 16 + lm;
        float bs = bias ? bias[col] : 0.f;
        float vv[4];
        #pragma unroll
        for (int r = 0; r < 4; r++) {
            int row = m0 + kg * 4 + r;
            float v = acc[ct][r] + ac2[ct][r] + bs;
            if (relu) v = fmaxf(v, 0.f);
            vv[r] = v;
            if (Cz)  Cz[(size_t)row * Nn + col] = v;
            if (Cbf) Cbf[(size_t)row * Nn + col] = f2bf(v);
        }
        if (vTout && col >= 2 * HCH) {              // uniform per tile (n0 % 64 == 0)
            ushort4 o;
            o.x = f2bf(vv[0]); o.y = f2bf(vv[1]); o.z = f2bf(vv[2]); o.w = f2bf(vv[3]);
            *(ushort4*)(vTout + (size_t)(col - 2 * HCH) * N + m0 + kg * 4) = o;
        }
    }
}

// --------------------------------------------- device attention for one i
// worker = 256 threads (tt). wgt LDS layout XOR-swizzled: ushort offset
// off(kk,kg,lm) = kk*512 + kg*128 + (lm*8 ^ ((kk&7)<<3)) — write spreads
// over all 32 banks, read stays a contiguous permuted 1024B block.
__device__ __forceinline__ void attn_one(
    int i, int tt, const float* __restrict__ qkv, const ushort* __restrict__ bias_l,
    const ushort* __restrict__ z_t, const ushort* __restrict__ vT,
    ushort* __restrict__ obuf, float* qs, const float* cj, ushort* wgt)
{
    const int w = tt >> 6, lane = tt & 63;
    const int lm = lane & 15, kg = lane >> 4;

    __syncthreads();                 // prior pass done with qs/wgt; cj written
    if (tt < HCH) qs[tt] = qkv[(size_t)i * QKVN + tt] * 0.25f;
    __syncthreads();

    const float cix = cj[i * 3 + 0], ciy = cj[i * 3 + 1], ciz = cj[i * 3 + 2];
    const int j0 = lane * 8;
    const int kkw = lane >> 2, kgw = lane & 3;
    const int wbase = kkw * 512 + kgw * 128;
    const int wsw   = (kkw & 7) << 3;

    #pragma unroll
    for (int e = 0; e < 4; e++) {
        const int h = w + 4 * e;
        ushort* wp = wgt + wbase + ((h * 8) ^ wsw);
        if (e == 3) { us8 zz = {}; *(us8*)wp = zz; continue; }   // pad rows 12..15
        float lg[8];
        us8 bl = *(const us8*)(bias_l + (size_t)h * NN2 + (size_t)i * N + j0);
        #pragma unroll
        for (int jj = 0; jj < 8; jj++) {
            const int j = j0 + jj;
            const float4* kp = (const float4*)(qkv + (size_t)j * QKVN + HCH + h * CH);
            const float4* qp = (const float4*)(qs + h * CH);
            float d = 0.f;
            #pragma unroll
            for (int cq = 0; cq < 4; cq++) {
                float4 kv = kp[cq], qv = qp[cq];
                d += qv.x * kv.x + qv.y * kv.y + qv.z * kv.z + qv.w * kv.w;
            }
            float dx = cix - cj[j * 3 + 0];
            float dy = ciy - cj[j * 3 + 1];
            float dz = ciz - cj[j * 3 + 2];
            float d2 = dx * dx + dy * dy + dz * dz;
            float ms = d2 <= 25.f ? 1.f : (d2 <= 225.f ? 0.3f : 0.05f);
            lg[jj] = d + bf2f(bl[jj]) + ms;
        }
        float mx = lg[0];
        #pragma unroll
        for (int jj = 1; jj < 8; jj++) mx = fmaxf(mx, lg[jj]);
        #pragma unroll
        for (int off = 32; off > 0; off >>= 1) mx = fmaxf(mx, __shfl_xor(mx, off));
        float ex[8], sm = 0.f;
        #pragma unroll
        for (int jj = 0; jj < 8; jj++) { ex[jj] = __expf(lg[jj] - mx); sm += ex[jj]; }
        #pragma unroll
        for (int off = 32; off > 0; off >>= 1) sm += __shfl_xor(sm, off);
        const float inv = 1.f / sm;
        us8 wv;
        #pragma unroll
        for (int jj = 0; jj < 8; jj++) wv[jj] = f2bf(ex[jj] * inv);
        *(us8*)wp = wv;
    }
    __syncthreads();

    // ---- pair + scalar MFMA off the shared wgt A-fragment ----
    const ushort* Bz = z_t + (size_t)i * CZ * N;
    f32x4 ap[2], as_[3];
    ap[0] = ap[1] = (f32x4){0.f, 0.f, 0.f, 0.f};
    as_[0] = as_[1] = as_[2] = (f32x4){0.f, 0.f, 0.f, 0.f};
    const int cbase = w * 32;
    const int pbase = 3 * w * 16;
    #pragma unroll 2
    for (int kk = 0; kk < 16; kk++) {
        bf16x8 a = *(const bf16x8*)(wgt + kk * 512 + ((lane * 8) ^ ((kk & 7) << 3)));
        const int ko = kk * 32 + kg * 8;
        #pragma unroll
        for (int ntl = 0; ntl < 2; ntl++) {
            bf16x8 b = *(const bf16x8*)(Bz + (size_t)(cbase + ntl * 16 + lm) * N + ko);
            ap[ntl] = __builtin_amdgcn_mfma_f32_16x16x32_bf16(a, b, ap[ntl], 0, 0, 0);
        }
        #pragma unroll
        for (int si = 0; si < 3; si++) {
            bf16x8 b = *(const bf16x8*)(vT + (size_t)(pbase + si * 16 + lm) * N + ko);
            as_[si] = __builtin_amdgcn_mfma_f32_16x16x32_bf16(a, b, as_[si], 0, 0, 0);
        }
    }
    const size_t ob = (size_t)i * OD;
    if (kg < 3) {
        #pragma unroll
        for (int ntl = 0; ntl < 2; ntl++)
            #pragma unroll
            for (int r = 0; r < 4; r++) {
                int h = kg * 4 + r;
                obuf[ob + h * 144 + 16 + cbase + ntl * 16 + lm] = f2bf(ap[ntl][r]);
            }
    }
    #pragma unroll
    for (int si = 0; si < 3; si++) {
        int ht = 3 * w + si;
        if (kg == (ht >> 2)) obuf[ob + ht * 144 + lm] = f2bf(as_[si][ht & 3]);
    }
}

// -------------- device LN over 4 rows (512 threads: row = t>>7, 128 thr/row)
template<int PARTS, bool COORD>
__device__ __forceinline__ void ln_rows4(
    const float* __restrict__ x, const float* __restrict__ gb,
    float* __restrict__ s, ushort* __restrict__ sbf,
    const float* __restrict__ g, const float* __restrict__ b,
    const float* __restrict__ Wu_l, const float* __restrict__ bu_l,
    float* __restrict__ coords, int i0, int t,
    float* redA /*[4][4]*/, float* redC /*[4][2][3]*/)
{
    const int rl = t >> 7, tt = t & 127;
    const int i = i0 + rl;
    const int wih = (t >> 6) & 1;
    float v[3];
    float sum = 0.f;
    #pragma unroll
    for (int e = 0; e < 3; e++) {
        int c = tt + e * 128;
        float a = s[(size_t)i * CS + c] + gb[c];
        #pragma unroll
        for (int p = 0; p < PARTS; p++) a += x[(size_t)p * N * CS + (size_t)i * CS + c];
        v[e] = a; sum += a;
    }
    #pragma unroll
    for (int off = 32; off > 0; off >>= 1) sum += __shfl_down(sum, off);
    if ((t & 63) == 0) redA[rl * 4 + wih] = sum;
    __syncthreads();
    float mu = (redA[rl * 4 + 0] + redA[rl * 4 + 1]) * (1.f / CS);
    float vs = 0.f;
    #pragma unroll
    for (int e = 0; e < 3; e++) { float d = v[e] - mu; vs += d * d; }
    #pragma unroll
    for (int off = 32; off > 0; off >>= 1) vs += __shfl_down(vs, off);
    if ((t & 63) == 0) redA[rl * 4 + 2 + wih] = vs;
    __syncthreads();
    float inv = rsqrtf((redA[rl * 4 + 2] + redA[rl * 4 + 3]) * (1.f / CS) + 1e-5f);
    float a0 = 0.f, a1 = 0.f, a2 = 0.f;
    #pragma unroll
    for (int e = 0; e < 3; e++) {
        int c = tt + e * 128;
        float ov = (v[e] - mu) * inv * g[c] + b[c];
        s[(size_t)i * CS + c]   = ov;
        sbf[(size_t)i * CS + c] = f2bf(ov);
        if (COORD) {
            a0 += ov * Wu_l[c * 6 + 0];
            a1 += ov * Wu_l[c * 6 + 1];
            a2 += ov * Wu_l[c * 6 + 2];
        }
    }
    if (COORD) {
        #pragma unroll
        for (int off = 32; off > 0; off >>= 1) {
            a0 += __shfl_down(a0, off);
            a1 += __shfl_down(a1, off);
            a2 += __shfl_down(a2, off);
        }
        if ((t & 63) == 0) {
            float* rc = redC + (rl * 2 + wih) * 3;
            rc[0] = a0; rc[1] = a1; rc[2] = a2;
        }
        __syncthreads();
        if (tt == 0) {
            const float* rA = redC + (rl * 2 + 0) * 3;
            const float* rB = redC + (rl * 2 + 1) * 3;
            coords[i * 3 + 0] += rA[0] + rB[0] + bu_l[0];
            coords[i * 3 + 1] += rA[1] + rB[1] + bu_l[1];
            coords[i * 3 + 2] += rA[2] + rB[2] + bu_l[2];
        }
    }
}

// ---------------------------------------------------------------- mega kernel
struct MegaArgs {
    const ushort* WqkvT; const float* bqkv;
    const ushort* WoT;   const float* bo;
    const ushort* Wt1T;  const float* bt1;
    const ushort* Wt2T;  const float* bt2;
    const float*  Wu;    const float* bu;
    const float*  lng;   const float* lnb;
    const ushort* bias_all; const ushort* z_t;
    float* qkv; float* tmp2; float* scur;
    ushort* vT; ushort* scur_bf; ushort* obuf_bf; ushort* tmp1_bf;
    float* coords;
    uint* flags;
};

__global__ __launch_bounds__(512) void mega(MegaArgs a)
{
    const int bid = blockIdx.x;
    const int t = threadIdx.x;
    const int half = t >> 8, tt = t & 255;
    const int W = bid + NB * half;          // worker id 0..511
    __shared__ float  qs[2][HCH];
    __shared__ float  cj[N * 3];
    __shared__ ushort wgt[2][16 * N];       // 2 x 16 KB
    __shared__ float  lnredA[16];
    __shared__ float  lnredC[24];
    uint bar = 0;

    for (int r = 0; r < RECY; r++)
    for (int l = 0; l < L; l++) {
        // S1: qkv = s @ Wqkv + b (+ fused vT)   72 tiles
        if (W < 72)
            gemm_tile(a.scur_bf, a.WqkvT + (size_t)l * CS * QKVN, a.bqkv + l * QKVN,
                      a.qkv, nullptr, a.vT, N, QKVN, CS, CS, 0,
                      W % 9, W / 9, 0, tt);
        gsync(a.flags, ++bar);
        // S2: attention, 1 i per worker (512 concurrent, 8 waves/CU)
        {
            #pragma unroll
            for (int e = 0; e < 3; e++) cj[e * 512 + t] = a.coords[e * 512 + t];
            attn_one(W, tt, a.qkv, a.bias_all + (size_t)l * H * NN2,
                     a.z_t, a.vT, a.obuf_bf, qs[half], cj, wgt[half]);
        }
        gsync(a.flags, ++bar);
        // S3: o @ Wo, split-K 9   (432 workers, kper=192)
        if (W < 432) {
            int bz = W / 48, rem = W % 48;
            gemm_tile(a.obuf_bf, a.WoT + (size_t)l * OD * CS, nullptr,
                      a.tmp2, nullptr, nullptr, N, CS, OD, 192, 0,
                      rem % 6, rem / 6, bz, tt);
        }
        gsync(a.flags, ++bar);
        // S4: LN1 (9 parts), 4 rows/block, blocks 0..127
        if (bid < 128)
            ln_rows4<9, false>(a.tmp2, a.bo + l * CS, a.scur, a.scur_bf,
                               a.lng + (size_t)(2 * l) * CS, a.lnb + (size_t)(2 * l) * CS,
                               nullptr, nullptr, nullptr, bid * 4, t, lnredA, lnredC);
        gsync(a.flags, ++bar);
        // S5: FFN1 relu  (192 workers)
        if (W < 192)
            gemm_tile(a.scur_bf, a.Wt1T + (size_t)l * CS * FF, a.bt1 + l * FF,
                      nullptr, a.tmp1_bf, nullptr, N, FF, CS, CS, 1,
                      W % 24, W / 24, 0, tt);
        gsync(a.flags, ++bar);
        // S6: FFN2, split-K 8  (384 workers, kper=192)
        if (W < 384) {
            int bz = W / 48, rem = W % 48;
            gemm_tile(a.tmp1_bf, a.Wt2T + (size_t)l * FF * CS, nullptr,
                      a.tmp2, nullptr, nullptr, N, CS, FF, 192, 0,
                      rem % 6, rem / 6, bz, tt);
        }
        gsync(a.flags, ++bar);
        // S7: LN2 (8 parts) + coord update, blocks 0..127
        if (bid < 128)
            ln_rows4<8, true>(a.tmp2, a.bt2 + l * CS, a.scur, a.scur_bf,
                              a.lng + (size_t)(2 * l + 1) * CS, a.lnb + (size_t)(2 * l + 1) * CS,
                              a.Wu + (size_t)l * CS * 6, a.bu + l * 6, a.coords,
                              bid * 4, t, lnredA, lnredC);
        gsync(a.flags, ++bar);
    }
}

// ---------------------------------------------------------------------- driver
extern "C" void kernel_launch(void* const* d_in, const int* in_sizes, int n_in,
                              void* d_out, int out_size, void* d_ws, size_t ws_size,
                              hipStream_t stream)
{
    const float* s_in = (const float*)d_in[0];
    const float* z    = (const float*)d_in[1];
    const float* Wq   = (const float*)d_in[2];
    const float* bq   = (const float*)d_in[3];
    const float* Wk   = (const float*)d_in[4];
    const float* bk   = (const float*)d_in[5];
    const float* Wv   = (const float*)d_in[6];
    const float* bv   = (const float*)d_in[7];
    const float* Wb   = (const float*)d_in[8];
    const float* bb   = (const float*)d_in[9];
    const float* Wo   = (const float*)d_in[10];
    const float* bo   = (const float*)d_in[11];
    const float* Wt1  = (const float*)d_in[12];
    const float* bt1  = (const float*)d_in[13];
    const float* Wt2  = (const float*)d_in[14];
    const float* bt2  = (const float*)d_in[15];
    const float* Wu   = (const float*)d_in[16];
    const float* bu   = (const float*)d_in[17];
    const float* lng  = (const float*)d_in[18];
    const float* lnb  = (const float*)d_in[19];
    float* coords = (float*)d_out;

    // ---- workspace carve ----
    float* wsf   = (float*)d_ws;
    float* qkv   = wsf;                              // N*QKVN
    float* tmp2  = qkv + (size_t)N * QKVN;           // 9*N*CS (split-K parts)
    float* scur  = tmp2 + (size_t)9 * N * CS;        // N*CS
    float* bqkv  = scur + (size_t)N * CS;            // L*QKVN
    ushort* wsu     = (ushort*)(bqkv + (size_t)L * QKVN);
    ushort* bias_all= wsu;                           // MB*N*N  bf16
    ushort* z_t     = bias_all + (size_t)MB * NN2;   // N*CZ*N (z transposed per i)
    ushort* WqkvT   = z_t + (size_t)N * CZ * N;
    ushort* WoT     = WqkvT + (size_t)L * CS * QKVN;
    ushort* Wt1T    = WoT + (size_t)L * OD * CS;
    ushort* Wt2T    = Wt1T + (size_t)L * CS * FF;
    ushort* WbT     = Wt2T + (size_t)L * FF * CS;    // MB*CZ
    ushort* vT      = WbT + (size_t)MB * CZ;         // HCH*N
    ushort* scur_bf = vT + (size_t)HCH * N;          // N*CS
    ushort* obuf_bf = scur_bf + (size_t)N * CS;      // N*OD
    ushort* tmp1_bf = obuf_bf + (size_t)N * OD;      // N*FF
    uint*   flags   = (uint*)(tmp1_bf + (size_t)N * FF);  // NB*16 uints (64B pad)
    (void)in_sizes; (void)n_in; (void)out_size; (void)ws_size;

    hipMemsetAsync(coords, 0, (size_t)N * 3 * sizeof(float), stream);
    hipMemsetAsync(flags, 0, (size_t)NB * 16 * sizeof(uint), stream);
    init_s<<<(N * CS) / 256, 256, 0, stream>>>(s_in, scur, scur_bf);
    pack_bqkv<<<(L * QKVN + 255) / 256, 256, 0, stream>>>(bq, bk, bv, bqkv);
    pack_qkv_t<<<dim3(CS / 32, QKVN / 32, L), 256, 0, stream>>>(Wq, Wk, Wv, WqkvT);
    transpose_w<<<dim3(OD / 32, CS / 32, L), 256, 0, stream>>>(Wo, WoT, OD, CS);
    transpose_w<<<dim3(CS / 32, FF / 32, L), 256, 0, stream>>>(Wt1, Wt1T, CS, FF);
    transpose_w<<<dim3(FF / 32, CS / 32, L), 256, 0, stream>>>(Wt2, Wt2T, FF, CS);
    transpose_w<<<dim3(N / 32, CZ / 32, N), 256, 0, stream>>>(z, z_t, N, CZ);   // z_t[i][c][j]
    pack_wbt<<<(MB * CZ) / 256, 256, 0, stream>>>(Wb, WbT);
    bias_gemm<<<(int)(NN2 / 256), 256, 0, stream>>>(WbT, z, bb, bias_all);

    MegaArgs ma;
    ma.WqkvT = WqkvT; ma.bqkv = bqkv;
    ma.WoT = WoT;     ma.bo = bo;
    ma.Wt1T = Wt1T;   ma.bt1 = bt1;
    ma.Wt2T = Wt2T;   ma.bt2 = bt2;
    ma.Wu = Wu;       ma.bu = bu;
    ma.lng = lng;     ma.lnb = lnb;
    ma.bias_all = bias_all; ma.z_t = z_t;
    ma.qkv = qkv; ma.tmp2 = tmp2; ma.scur = scur;
    ma.vT = vT; ma.scur_bf = scur_bf; ma.obuf_bf = obuf_bf; ma.tmp1_bf = tmp1_bf;
    ma.coords = coords;
    ma.flags = flags;
    mega<<<NB, 512, 0, stream>>>(ma);
}

// Round 6
// 3102.934 us; speedup vs baseline: 3.6505x; 3.6505x over previous
//
#include <hip/hip_runtime.h>

// StructureModule on MI355X — round 9: back to per-stage dispatches (round-5
// structure; software grid barriers cost >= 30us cross-XCD, worse than the
// ~9us graph-replay launch). New: everything after attention is row-local ->
// single `rowfused` kernel (Wo+LN1+FFN1+FFN2+LN2+coords, 32 blocks x 16 rows,
// LDS-resident intermediates). 7 -> 3 dispatches/layer.

constexpr int N    = 512;
constexpr int CS   = 384;
constexpr int CZ   = 128;
constexpr int CH   = 16;
constexpr int H    = 12;
constexpr int L    = 8;
constexpr int RECY = 2;
constexpr int HCH  = H * CH;        // 192
constexpr int QKVN = 3 * HCH;       // 576
constexpr int OD   = H * (CH + CZ); // 1728
constexpr int FF   = 4 * CS;        // 1536
constexpr int MB   = 96;            // bias columns = L*H
constexpr long long NN2 = (long long)N * N;

typedef __bf16 bf16x8 __attribute__((ext_vector_type(8)));
typedef float  f32x4  __attribute__((ext_vector_type(4)));
typedef unsigned short us8 __attribute__((ext_vector_type(8)));

__device__ __forceinline__ ushort f2bf(float f) {
    uint u = __builtin_bit_cast(uint, f);
    return (ushort)((u + 0x7fffu + ((u >> 16) & 1u)) >> 16);   // RNE
}
__device__ __forceinline__ float bf2f(ushort h) {
    uint u = ((uint)h) << 16;
    return __builtin_bit_cast(float, u);
}

// ----------------------------------------------------- init s (f32 + bf16 copy)
__global__ __launch_bounds__(256) void init_s(
    const float* __restrict__ s_in, float* __restrict__ scur, ushort* __restrict__ sbf)
{
    int i = blockIdx.x * 256 + threadIdx.x;
    float v = s_in[i];
    scur[i] = v;
    sbf[i]  = f2bf(v);
}

// ------------------------------------------------------------- pack bq|bk|bv
__global__ __launch_bounds__(256) void pack_bqkv(
    const float* __restrict__ bq, const float* __restrict__ bk,
    const float* __restrict__ bv, float* __restrict__ bqkv)
{
    int idx = blockIdx.x * 256 + threadIdx.x;
    if (idx >= L * QKVN) return;
    int n = idx % QKVN, l = idx / QKVN;
    int sel = n / HCH, nn = n % HCH;
    const float* bp = sel == 0 ? bq : (sel == 1 ? bk : bv);
    bqkv[idx] = bp[l * HCH + nn];
}

// ---------------------- pack Wq|Wk|Wv transposed to bf16 [l][n][k] (n-major)
__global__ __launch_bounds__(256) void pack_qkv_t(
    const float* __restrict__ Wq, const float* __restrict__ Wk,
    const float* __restrict__ Wv, ushort* __restrict__ WqkvT)
{
    __shared__ float tile[32][33];
    const int l = blockIdx.z;
    const int k0 = blockIdx.x * 32, n0 = blockIdx.y * 32;
    const int tx = threadIdx.x & 31, ty = threadIdx.x >> 5;
    const int sel = n0 / HCH;
    const int nn0 = n0 - sel * HCH;
    const float* W = sel == 0 ? Wq : (sel == 1 ? Wk : Wv);
    #pragma unroll
    for (int r = 0; r < 32; r += 8)
        tile[ty + r][tx] = W[((size_t)l * CS + k0 + ty + r) * HCH + nn0 + tx];
    __syncthreads();
    #pragma unroll
    for (int r = 0; r < 32; r += 8)
        WqkvT[((size_t)l * QKVN + n0 + ty + r) * CS + k0 + tx] = f2bf(tile[tx][ty + r]);
}

// ------------- generic transpose+convert: (G,K,Nn) f32 -> (G,Nn,K) bf16
__global__ __launch_bounds__(256) void transpose_w(
    const float* __restrict__ in, ushort* __restrict__ out, int K, int Nn)
{
    __shared__ float tile[32][33];
    const int l = blockIdx.z;
    const float* ip = in + (size_t)l * K * Nn;
    ushort* op = out + (size_t)l * K * Nn;
    const int k0 = blockIdx.x * 32, n0 = blockIdx.y * 32;
    const int tx = threadIdx.x & 31, ty = threadIdx.x >> 5;
    #pragma unroll
    for (int r = 0; r < 32; r += 8)
        tile[ty + r][tx] = ip[(size_t)(k0 + ty + r) * Nn + n0 + tx];
    __syncthreads();
    #pragma unroll
    for (int r = 0; r < 32; r += 8)
        op[(size_t)(n0 + ty + r) * K + k0 + tx] = f2bf(tile[tx][ty + r]);
}

// -------------------------------------- WbT[m=l*12+h][c] = Wb[l][c][h] (bf16)
__global__ __launch_bounds__(256) void pack_wbt(
    const float* __restrict__ Wb, ushort* __restrict__ WbT)
{
    int idx = blockIdx.x * 256 + threadIdx.x;     // MB*CZ = 12288
    int m = idx >> 7, c = idx & 127;
    int l = m / H, h = m % H;
    WbT[idx] = f2bf(Wb[((size_t)l * CZ + c) * H + h]);
}

// -------------------- bias_all[m][ij] = sum_c WbT[m][c]*z[ij][c] + bb[m]
__global__ __launch_bounds__(256) void bias_gemm(
    const ushort* __restrict__ WbT, const float* __restrict__ z,
    const float* __restrict__ bb, ushort* __restrict__ bias_all)
{
    const int w = threadIdx.x >> 6, lane = threadIdx.x & 63;
    const int lm = lane & 15, kg = lane >> 4;
    const size_t ij0 = (size_t)blockIdx.x * 256 + (size_t)w * 64;
    __shared__ float bbs[MB];
    if (threadIdx.x < MB) bbs[threadIdx.x] = bb[threadIdx.x];
    __syncthreads();
    f32x4 acc[6][4];
    #pragma unroll
    for (int mt = 0; mt < 6; mt++)
        #pragma unroll
        for (int nt = 0; nt < 4; nt++) acc[mt][nt] = (f32x4){0.f, 0.f, 0.f, 0.f};
    #pragma unroll
    for (int kc = 0; kc < 4; kc++) {
        const int k = kc * 32 + kg * 8;
        bf16x8 b[4];
        #pragma unroll
        for (int nt = 0; nt < 4; nt++) {
            const float* zp = z + (ij0 + nt * 16 + lm) * CZ + k;
            float4 z0 = *(const float4*)zp, z1 = *(const float4*)(zp + 4);
            b[nt][0] = (__bf16)z0.x; b[nt][1] = (__bf16)z0.y;
            b[nt][2] = (__bf16)z0.z; b[nt][3] = (__bf16)z0.w;
            b[nt][4] = (__bf16)z1.x; b[nt][5] = (__bf16)z1.y;
            b[nt][6] = (__bf16)z1.z; b[nt][7] = (__bf16)z1.w;
        }
        #pragma unroll
        for (int mt = 0; mt < 6; mt++) {
            bf16x8 a = *(const bf16x8*)(WbT + (size_t)(mt * 16 + lm) * CZ + k);
            #pragma unroll
            for (int nt = 0; nt < 4; nt++)
                acc[mt][nt] = __builtin_amdgcn_mfma_f32_16x16x32_bf16(a, b[nt], acc[mt][nt], 0, 0, 0);
        }
    }
    #pragma unroll
    for (int mt = 0; mt < 6; mt++)
        #pragma unroll
        for (int nt = 0; nt < 4; nt++)
            #pragma unroll
            for (int r = 0; r < 4; r++) {
                int m = mt * 16 + kg * 4 + r;
                bias_all[(size_t)m * NN2 + ij0 + nt * 16 + lm] = f2bf(acc[mt][nt][r] + bbs[m]);
            }
}

// ----------------------------------------------------------- bf16 MFMA GEMM
// (qkv only now.) Dual K-chain ILP; fused transposed write of the V block.
__global__ __launch_bounds__(256) void gemm_bf16(
    const ushort* __restrict__ A, const ushort* __restrict__ Bt,
    const float* __restrict__ bias, float* __restrict__ C,
    ushort* __restrict__ vTout, int M, int Nn, int K, int kper)
{
    const int w = threadIdx.x >> 6, lane = threadIdx.x & 63;
    const int lm = lane & 15, kg = lane >> 4;
    const int m0 = blockIdx.y * 64 + w * 16;
    const int n0 = blockIdx.x * 64;
    const int kh = kper >> 1;
    const ushort* Ap  = A  + (size_t)(m0 + lm) * K + kg * 8;
    const ushort* Bp  = Bt + (size_t)(n0 + lm) * K + kg * 8;
    f32x4 acc[4], ac2[4];
    #pragma unroll
    for (int ct = 0; ct < 4; ct++) {
        acc[ct] = (f32x4){0.f, 0.f, 0.f, 0.f};
        ac2[ct] = (f32x4){0.f, 0.f, 0.f, 0.f};
    }
    for (int k = 0; k < kh; k += 32) {
        bf16x8 a0 = *(const bf16x8*)(Ap + k);
        bf16x8 a1 = *(const bf16x8*)(Ap + kh + k);
        #pragma unroll
        for (int ct = 0; ct < 4; ct++) {
            bf16x8 b0 = *(const bf16x8*)(Bp + (size_t)ct * 16 * K + k);
            bf16x8 b1 = *(const bf16x8*)(Bp + (size_t)ct * 16 * K + kh + k);
            acc[ct] = __builtin_amdgcn_mfma_f32_16x16x32_bf16(a0, b0, acc[ct], 0, 0, 0);
            ac2[ct] = __builtin_amdgcn_mfma_f32_16x16x32_bf16(a1, b1, ac2[ct], 0, 0, 0);
        }
    }
    #pragma unroll
    for (int ct = 0; ct < 4; ct++) {
        int col = n0 + ct * 16 + lm;
        float bs = bias[col];
        float vv[4];
        #pragma unroll
        for (int r = 0; r < 4; r++) {
            int row = m0 + kg * 4 + r;
            float v = acc[ct][r] + ac2[ct][r] + bs;
            vv[r] = v;
            C[(size_t)row * Nn + col] = v;
        }
        if (col >= 2 * HCH) {                        // uniform per tile
            ushort4 o;
            o.x = f2bf(vv[0]); o.y = f2bf(vv[1]); o.z = f2bf(vv[2]); o.w = f2bf(vv[3]);
            *(ushort4*)(vTout + (size_t)(col - 2 * HCH) * N + m0 + kg * 4) = o;
        }
    }
}

// ---------------------------------------------------------- fused attention
// One block per i (4 waves) — unchanged from the verified round-5 kernel.
__global__ __launch_bounds__(256) void attn_fused(
    const float* __restrict__ qkv, const ushort* __restrict__ bias_l,
    const float* __restrict__ coords, const ushort* __restrict__ z_t,
    const ushort* __restrict__ vT, ushort* __restrict__ obuf)
{
    const int i = blockIdx.x, t = threadIdx.x;
    const int w = t >> 6, lane = t & 63;
    const int lm = lane & 15, kg = lane >> 4;
    __shared__ float  qs[HCH];
    __shared__ float  cj[N * 3];
    __shared__ ushort wgt[16 * N];    // 16 KB

    if (t < HCH) qs[t] = qkv[(size_t)i * QKVN + t] * 0.25f;
    #pragma unroll
    for (int e = 0; e < 6; e++) cj[e * 256 + t] = coords[e * 256 + t];
    __syncthreads();

    const float cix = cj[i * 3 + 0], ciy = cj[i * 3 + 1], ciz = cj[i * 3 + 2];
    const int j0 = lane * 8;
    const int slot_us = (lane >> 2) * 512 + (lane & 3) * 128;   // + h*8

    #pragma unroll
    for (int e = 0; e < 4; e++) {
        const int h = w + 4 * e;
        ushort* wp = wgt + slot_us + h * 8;
        if (e == 3) { us8 zz = {}; *(us8*)wp = zz; continue; }   // pad rows 12..15
        float lg[8];
        us8 bl = *(const us8*)(bias_l + (size_t)h * NN2 + (size_t)i * N + j0);
        #pragma unroll
        for (int jj = 0; jj < 8; jj++) {
            const int j = j0 + jj;
            const float4* kp = (const float4*)(qkv + (size_t)j * QKVN + HCH + h * CH);
            const float4* qp = (const float4*)(qs + h * CH);
            float d = 0.f;
            #pragma unroll
            for (int cq = 0; cq < 4; cq++) {
                float4 kv = kp[cq], qv = qp[cq];
                d += qv.x * kv.x + qv.y * kv.y + qv.z * kv.z + qv.w * kv.w;
            }
            float dx = cix - cj[j * 3 + 0];
            float dy = ciy - cj[j * 3 + 1];
            float dz = ciz - cj[j * 3 + 2];
            float d2 = dx * dx + dy * dy + dz * dz;
            float ms = d2 <= 25.f ? 1.f : (d2 <= 225.f ? 0.3f : 0.05f);
            lg[jj] = d + bf2f(bl[jj]) + ms;
        }
        float mx = lg[0];
        #pragma unroll
        for (int jj = 1; jj < 8; jj++) mx = fmaxf(mx, lg[jj]);
        #pragma unroll
        for (int off = 32; off > 0; off >>= 1) mx = fmaxf(mx, __shfl_xor(mx, off));
        float ex[8], sm = 0.f;
        #pragma unroll
        for (int jj = 0; jj < 8; jj++) { ex[jj] = __expf(lg[jj] - mx); sm += ex[jj]; }
        #pragma unroll
        for (int off = 32; off > 0; off >>= 1) sm += __shfl_xor(sm, off);
        const float inv = 1.f / sm;
        us8 wv;
        #pragma unroll
        for (int jj = 0; jj < 8; jj++) wv[jj] = f2bf(ex[jj] * inv);
        *(us8*)wp = wv;
    }
    __syncthreads();

    const ushort* Bz = z_t + (size_t)i * CZ * N;
    f32x4 ap[2], as_[3];
    ap[0] = ap[1] = (f32x4){0.f, 0.f, 0.f, 0.f};
    as_[0] = as_[1] = as_[2] = (f32x4){0.f, 0.f, 0.f, 0.f};
    const int cbase = w * 32;
    const int pbase = 3 * w * 16;
    #pragma unroll 2
    for (int kk = 0; kk < 16; kk++) {
        bf16x8 a = *(const bf16x8*)(wgt + kk * 512 + lane * 8);
        const int ko = kk * 32 + kg * 8;
        #pragma unroll
        for (int ntl = 0; ntl < 2; ntl++) {
            bf16x8 b = *(const bf16x8*)(Bz + (size_t)(cbase + ntl * 16 + lm) * N + ko);
            ap[ntl] = __builtin_amdgcn_mfma_f32_16x16x32_bf16(a, b, ap[ntl], 0, 0, 0);
        }
        #pragma unroll
        for (int si = 0; si < 3; si++) {
            bf16x8 b = *(const bf16x8*)(vT + (size_t)(pbase + si * 16 + lm) * N + ko);
            as_[si] = __builtin_amdgcn_mfma_f32_16x16x32_bf16(a, b, as_[si], 0, 0, 0);
        }
    }
    const size_t ob = (size_t)i * OD;
    if (kg < 3) {
        #pragma unroll
        for (int ntl = 0; ntl < 2; ntl++)
            #pragma unroll
            for (int r = 0; r < 4; r++) {
                int h = kg * 4 + r;
                obuf[ob + h * 144 + 16 + cbase + ntl * 16 + lm] = f2bf(ap[ntl][r]);
            }
    }
    #pragma unroll
    for (int si = 0; si < 3; si++) {
        int ht = 3 * w + si;
        if (kg == (ht >> 2)) obuf[ob + ht * 144 + lm] = f2bf(as_[si][ht & 3]);
    }
}

// ---------------------------------------------- row-local layer remainder
// 32 blocks x 512 threads (8 waves); block owns rows i0..i0+15.
// obuf(LDS) -> Wo -> LN1 -> FFN1 -> FFN2 -> LN2 -> s/scur_bf/coords.
// A-fragments in LDS use a 16B-block XOR swizzle (col8 ^ (row&3)<<3) so the
// 16 lm-lanes spread across banks on ds_read_b128.
__global__ __launch_bounds__(512) void rowfused(
    const ushort* __restrict__ obuf, const ushort* __restrict__ Wo_l,
    const float* __restrict__ bo_l,
    const ushort* __restrict__ Wt1_l, const float* __restrict__ bt1_l,
    const ushort* __restrict__ Wt2_l, const float* __restrict__ bt2_l,
    const float* __restrict__ Wu_l, const float* __restrict__ bu_l,
    const float* __restrict__ g1, const float* __restrict__ b1,
    const float* __restrict__ g2, const float* __restrict__ b2,
    float* __restrict__ scur, ushort* __restrict__ sbf_g,
    float* __restrict__ coords)
{
    constexpr int OBS = 1736;   // ob row stride (ushorts)
    constexpr int T1S = 1544;   // t1 row stride
    constexpr int SAS = 388;    // sar row stride (f32)
    constexpr int SBS = 392;    // sbf row stride
    __shared__ ushort obt1[16 * OBS];   // 55.5 KB: obuf rows, then t1
    __shared__ float  sar[16 * SAS];    // 24.8 KB: f32 row state
    __shared__ ushort sbf[16 * SBS];    // 12.5 KB: LN1 out (bf16)

    const int t = threadIdx.x, w = t >> 6, lane = t & 63;
    const int lm = lane & 15, kg = lane >> 4;
    const int i0 = blockIdx.x * 16;
    const int aswz = (lm & 3) << 3;

    // ---- stage obuf rows into LDS (swizzled 16B blocks) ----
    for (int v = t; v < 16 * (OD / 8); v += 512) {
        int row = v / (OD / 8), c8 = (v % (OD / 8)) * 8;
        *(us8*)&obt1[row * OBS + (c8 ^ ((row & 3) << 3))] =
            *(const us8*)&obuf[(size_t)(i0 + row) * OD + c8];
    }
    __syncthreads();

    f32x4 acc[12], ac2[3];

    // ---- Wo: 16x384 = ob @ WoT, K=1728 dual-chain; wave w -> cols w*48.. ----
    #pragma unroll
    for (int ct = 0; ct < 3; ct++) {
        acc[ct] = (f32x4){0.f, 0.f, 0.f, 0.f};
        ac2[ct] = (f32x4){0.f, 0.f, 0.f, 0.f};
    }
    for (int k = 0; k < 864; k += 32) {
        const int ka = kg * 8 + k;
        bf16x8 a0 = *(const bf16x8*)&obt1[lm * OBS + (ka ^ aswz)];
        bf16x8 a1 = *(const bf16x8*)&obt1[lm * OBS + ((ka + 864) ^ aswz)];
        #pragma unroll
        for (int ct = 0; ct < 3; ct++) {
            const ushort* bp = Wo_l + (size_t)(w * 48 + ct * 16 + lm) * OD + ka;
            acc[ct] = __builtin_amdgcn_mfma_f32_16x16x32_bf16(a0, *(const bf16x8*)bp, acc[ct], 0, 0, 0);
            ac2[ct] = __builtin_amdgcn_mfma_f32_16x16x32_bf16(a1, *(const bf16x8*)(bp + 864), ac2[ct], 0, 0, 0);
        }
    }
    #pragma unroll
    for (int ct = 0; ct < 3; ct++) {
        int col = w * 48 + ct * 16 + lm;
        float bs = bo_l[col];
        #pragma unroll
        for (int rr = 0; rr < 4; rr++) {
            int row = kg * 4 + rr;
            sar[row * SAS + col] = acc[ct][rr] + ac2[ct][rr] + bs
                                 + scur[(size_t)(i0 + row) * CS + col];
        }
    }
    __syncthreads();

    // ---- LN1: 32 threads per row ----
    {
        const int r = t >> 5, l32 = t & 31;
        float vv[12], sum = 0.f;
        #pragma unroll
        for (int e = 0; e < 12; e++) { vv[e] = sar[r * SAS + l32 + e * 32]; sum += vv[e]; }
        #pragma unroll
        for (int off = 16; off > 0; off >>= 1) sum += __shfl_xor(sum, off);
        float mu = sum * (1.f / CS);
        float vs = 0.f;
        #pragma unroll
        for (int e = 0; e < 12; e++) { float d = vv[e] - mu; vs += d * d; }
        #pragma unroll
        for (int off = 16; off > 0; off >>= 1) vs += __shfl_xor(vs, off);
        float inv = rsqrtf(vs * (1.f / CS) + 1e-5f);
        #pragma unroll
        for (int e = 0; e < 12; e++) {
            int c = l32 + e * 32;
            float o = (vv[e] - mu) * inv * g1[c] + b1[c];
            sar[r * SAS + c] = o;                 // keep f32 for LN2 residual
            sbf[r * SBS + c] = f2bf(o);
        }
    }
    __syncthreads();

    // ---- FFN1: 16x1536 = sbf @ Wt1T, relu -> t1 (in obt1, stride T1S) ----
    #pragma unroll
    for (int ct = 0; ct < 12; ct++) acc[ct] = (f32x4){0.f, 0.f, 0.f, 0.f};
    for (int k = 0; k < 384; k += 32) {
        bf16x8 a = *(const bf16x8*)&sbf[lm * SBS + kg * 8 + k];
        #pragma unroll
        for (int ct = 0; ct < 12; ct++) {
            const ushort* bp = Wt1_l + (size_t)(w * 192 + ct * 16 + lm) * CS + kg * 8 + k;
            acc[ct] = __builtin_amdgcn_mfma_f32_16x16x32_bf16(a, *(const bf16x8*)bp, acc[ct], 0, 0, 0);
        }
    }
    #pragma unroll
    for (int ct = 0; ct < 12; ct++) {
        int col = w * 192 + ct * 16 + lm;
        float bs = bt1_l[col];
        #pragma unroll
        for (int rr = 0; rr < 4; rr++) {
            int row = kg * 4 + rr;
            float v = fmaxf(acc[ct][rr] + bs, 0.f);
            obt1[row * T1S + (((col & ~7) ^ ((row & 3) << 3)) | (col & 7))] = f2bf(v);
        }
    }
    __syncthreads();

    // ---- FFN2: 16x384 = t1 @ Wt2T, K=1536 dual-chain; += into sar ----
    #pragma unroll
    for (int ct = 0; ct < 3; ct++) {
        acc[ct] = (f32x4){0.f, 0.f, 0.f, 0.f};
        ac2[ct] = (f32x4){0.f, 0.f, 0.f, 0.f};
    }
    for (int k = 0; k < 768; k += 32) {
        const int ka = kg * 8 + k;
        bf16x8 a0 = *(const bf16x8*)&obt1[lm * T1S + (ka ^ aswz)];
        bf16x8 a1 = *(const bf16x8*)&obt1[lm * T1S + ((ka + 768) ^ aswz)];
        #pragma unroll
        for (int ct = 0; ct < 3; ct++) {
            const ushort* bp = Wt2_l + (size_t)(w * 48 + ct * 16 + lm) * FF + ka;
            acc[ct] = __builtin_amdgcn_mfma_f32_16x16x32_bf16(a0, *(const bf16x8*)bp, acc[ct], 0, 0, 0);
            ac2[ct] = __builtin_amdgcn_mfma_f32_16x16x32_bf16(a1, *(const bf16x8*)(bp + 768), ac2[ct], 0, 0, 0);
        }
    }
    #pragma unroll
    for (int ct = 0; ct < 3; ct++) {
        int col = w * 48 + ct * 16 + lm;
        float bs = bt2_l[col];
        #pragma unroll
        for (int rr = 0; rr < 4; rr++) {
            int row = kg * 4 + rr;
            sar[row * SAS + col] += acc[ct][rr] + ac2[ct][rr] + bs;
        }
    }
    __syncthreads();

    // ---- LN2 + global write + coord update ----
    {
        const int r = t >> 5, l32 = t & 31;
        float vv[12], sum = 0.f;
        #pragma unroll
        for (int e = 0; e < 12; e++) { vv[e] = sar[r * SAS + l32 + e * 32]; sum += vv[e]; }
        #pragma unroll
        for (int off = 16; off > 0; off >>= 1) sum += __shfl_xor(sum, off);
        float mu = sum * (1.f / CS);
        float vs = 0.f;
        #pragma unroll
        for (int e = 0; e < 12; e++) { float d = vv[e] - mu; vs += d * d; }
        #pragma unroll
        for (int off = 16; off > 0; off >>= 1) vs += __shfl_xor(vs, off);
        float inv = rsqrtf(vs * (1.f / CS) + 1e-5f);
        float a0 = 0.f, a1 = 0.f, a2 = 0.f;
        #pragma unroll
        for (int e = 0; e < 12; e++) {
            int c = l32 + e * 32;
            float o = (vv[e] - mu) * inv * g2[c] + b2[c];
            scur[(size_t)(i0 + r) * CS + c]  = o;
            sbf_g[(size_t)(i0 + r) * CS + c] = f2bf(o);
            a0 += o * Wu_l[c * 6 + 0];
            a1 += o * Wu_l[c * 6 + 1];
            a2 += o * Wu_l[c * 6 + 2];
        }
        #pragma unroll
        for (int off = 16; off > 0; off >>= 1) {
            a0 += __shfl_xor(a0, off);
            a1 += __shfl_xor(a1, off);
            a2 += __shfl_xor(a2, off);
        }
        if (l32 == 0) {
            coords[(i0 + r) * 3 + 0] += a0 + bu_l[0];
            coords[(i0 + r) * 3 + 1] += a1 + bu_l[1];
            coords[(i0 + r) * 3 + 2] += a2 + bu_l[2];
        }
    }
}

// ---------------------------------------------------------------------- driver
extern "C" void kernel_launch(void* const* d_in, const int* in_sizes, int n_in,
                              void* d_out, int out_size, void* d_ws, size_t ws_size,
                              hipStream_t stream)
{
    const float* s_in = (const float*)d_in[0];
    const float* z    = (const float*)d_in[1];
    const float* Wq   = (const float*)d_in[2];
    const float* bq   = (const float*)d_in[3];
    const float* Wk   = (const float*)d_in[4];
    const float* bk   = (const float*)d_in[5];
    const float* Wv   = (const float*)d_in[6];
    const float* bv   = (const float*)d_in[7];
    const float* Wb   = (const float*)d_in[8];
    const float* bb   = (const float*)d_in[9];
    const float* Wo   = (const float*)d_in[10];
    const float* bo   = (const float*)d_in[11];
    const float* Wt1  = (const float*)d_in[12];
    const float* bt1  = (const float*)d_in[13];
    const float* Wt2  = (const float*)d_in[14];
    const float* bt2  = (const float*)d_in[15];
    const float* Wu   = (const float*)d_in[16];
    const float* bu   = (const float*)d_in[17];
    const float* lng  = (const float*)d_in[18];
    const float* lnb  = (const float*)d_in[19];
    float* coords = (float*)d_out;

    // ---- workspace carve ----
    float* wsf   = (float*)d_ws;
    float* qkv   = wsf;                              // N*QKVN
    float* scur  = qkv + (size_t)N * QKVN;           // N*CS
    float* bqkv  = scur + (size_t)N * CS;            // L*QKVN
    ushort* wsu     = (ushort*)(bqkv + (size_t)L * QKVN);
    ushort* bias_all= wsu;                           // MB*N*N  bf16
    ushort* z_t     = bias_all + (size_t)MB * NN2;   // N*CZ*N
    ushort* WqkvT   = z_t + (size_t)N * CZ * N;
    ushort* WoT     = WqkvT + (size_t)L * CS * QKVN;
    ushort* Wt1T    = WoT + (size_t)L * OD * CS;
    ushort* Wt2T    = Wt1T + (size_t)L * CS * FF;
    ushort* WbT     = Wt2T + (size_t)L * FF * CS;    // MB*CZ
    ushort* vT      = WbT + (size_t)MB * CZ;         // HCH*N
    ushort* scur_bf = vT + (size_t)HCH * N;          // N*CS
    ushort* obuf_bf = scur_bf + (size_t)N * CS;      // N*OD
    (void)in_sizes; (void)n_in; (void)out_size; (void)ws_size;

    hipMemsetAsync(coords, 0, (size_t)N * 3 * sizeof(float), stream);
    init_s<<<(N * CS) / 256, 256, 0, stream>>>(s_in, scur, scur_bf);
    pack_bqkv<<<(L * QKVN + 255) / 256, 256, 0, stream>>>(bq, bk, bv, bqkv);
    pack_qkv_t<<<dim3(CS / 32, QKVN / 32, L), 256, 0, stream>>>(Wq, Wk, Wv, WqkvT);
    transpose_w<<<dim3(OD / 32, CS / 32, L), 256, 0, stream>>>(Wo, WoT, OD, CS);
    transpose_w<<<dim3(CS / 32, FF / 32, L), 256, 0, stream>>>(Wt1, Wt1T, CS, FF);
    transpose_w<<<dim3(FF / 32, CS / 32, L), 256, 0, stream>>>(Wt2, Wt2T, FF, CS);
    transpose_w<<<dim3(N / 32, CZ / 32, N), 256, 0, stream>>>(z, z_t, N, CZ);   // z_t[i][c][j]
    pack_wbt<<<(MB * CZ) / 256, 256, 0, stream>>>(Wb, WbT);
    bias_gemm<<<(int)(NN2 / 256), 256, 0, stream>>>(WbT, z, bb, bias_all);

    for (int r = 0; r < RECY; r++) {
        for (int l = 0; l < L; l++) {
            // S1: qkv = s @ Wqkv + bqkv (+ fused vT)   (M=512, N=576, K=384)
            gemm_bf16<<<dim3(QKVN / 64, N / 64, 1), 256, 0, stream>>>(
                scur_bf, WqkvT + (size_t)l * CS * QKVN, bqkv + l * QKVN,
                qkv, vT, N, QKVN, CS, CS);
            // S2: attention
            attn_fused<<<N, 256, 0, stream>>>(
                qkv, bias_all + (size_t)l * H * NN2, coords, z_t, vT, obuf_bf);
            // S3: row-local remainder (Wo+LN1+FFN1+FFN2+LN2+coords)
            rowfused<<<N / 16, 512, 0, stream>>>(
                obuf_bf, WoT + (size_t)l * OD * CS, bo + l * CS,
                Wt1T + (size_t)l * CS * FF, bt1 + l * FF,
                Wt2T + (size_t)l * FF * CS, bt2 + l * CS,
                Wu + (size_t)l * CS * 6, bu + l * 6,
                lng + (size_t)(2 * l) * CS, lnb + (size_t)(2 * l) * CS,
                lng + (size_t)(2 * l + 1) * CS, lnb + (size_t)(2 * l + 1) * CS,
                scur, scur_bf, coords);
        }
    }
}